// Round 6
// baseline (410.166 us; speedup 1.0000x reference)
//
#include <hip/hip_runtime.h>
#include <hip/hip_bf16.h>

// Sizes
// B=8, N=1024, S=16, C=3, H=8, DIM=768, HD=96, SCALE=96^-0.5, BN_EPS=1e-3
//
// Algebraic restructuring (R5): out = BN(P@W_re)@V collapses to
//   out[n][d] = sum_m P[n][m] * M2[m][d] + cv[d]
//   M2[m][d]  = sum_p W_re[m][p] * G[p] * V[p][d]      (12.9 GF, batched bh)
//   cv[d]     = sum_p Cc[p] * V[p][d]
// R6: XCD-aware block swizzles (attn, m2), deferred softmax normalization,
//     coalesced w_proj transpose, 4-token conv blocks, fat cv blocks.

typedef __attribute__((ext_vector_type(4))) float f32x4;
typedef __bf16 __attribute__((ext_vector_type(8))) bf16x8;

__device__ __forceinline__ unsigned short f2bf(float x){
  unsigned u = __builtin_bit_cast(unsigned, x);
  u += 0x7fffu + ((u >> 16) & 1u);          // round-to-nearest-even
  return (unsigned short)(u >> 16);
}

__device__ __forceinline__ float bf2f(unsigned short u){
  unsigned v = (unsigned)u << 16;
  return __builtin_bit_cast(float, v);
}

__device__ __forceinline__ f32x4 mfma16(bf16x8 a, bf16x8 b, f32x4 c){
  return __builtin_amdgcn_mfma_f32_16x16x32_bf16(a, b, c, 0, 0, 0);
}

__device__ __forceinline__ bf16x8 ld8(const unsigned short* p){
  return *reinterpret_cast<const bf16x8*>(p);
}

// ---------------------------------------------------------------------------
// Prep: Wre_rm[m][p] = bf16(w_re[m][p]) (coalesced cast);
//       G[p] = gamma*rsqrt(var+eps); Cc=(b_re-mean)*G+beta; CoverG=Cc/G
// ---------------------------------------------------------------------------
__global__ void prep_kernel(const float* __restrict__ w_re, const float* __restrict__ b_re,
                            const float* __restrict__ gma, const float* __restrict__ beta,
                            const float* __restrict__ mean, const float* __restrict__ var,
                            unsigned short* __restrict__ Wre_rm,
                            float* __restrict__ G, float* __restrict__ Cc,
                            float* __restrict__ CoverG)
{
  int idx = blockIdx.x * 256 + threadIdx.x;
  if (idx < 1024*1024){
    Wre_rm[idx] = f2bf(w_re[idx]);
  } else if (idx < 1024*1024 + 1024){
    int p = idx - 1024*1024;
    float g = gma[p] * rsqrtf(var[p] + 1e-3f);
    float cc = (b_re[p] - mean[p]) * g + beta[p];
    G[p] = g;
    Cc[p] = cc;
    CoverG[p] = cc / g;
  }
}

// ---------------------------------------------------------------------------
// Wpt[o][i] = bf16(w_proj[i][o]) via LDS 64x64 tiles (coalesced both sides)
// ---------------------------------------------------------------------------
__global__ __launch_bounds__(256) void wpt_kernel(const float* __restrict__ wp,
                                                  unsigned short* __restrict__ Wpt)
{
  __shared__ float t[64][65];
  const int i0 = blockIdx.x * 64, o0 = blockIdx.y * 64;
  const int r = threadIdx.x >> 6;        // 0..3
  const int c = threadIdx.x & 63;        // 0..63
#pragma unroll
  for (int rep = 0; rep < 16; ++rep){
    int row = rep*4 + r;
    t[row][c] = wp[(size_t)(i0 + row)*768 + o0 + c];
  }
  __syncthreads();
#pragma unroll
  for (int rep = 0; rep < 16; ++rep){
    int orow = rep*4 + r;
    Wpt[(size_t)(o0 + orow)*768 + i0 + c] = f2bf(t[c][orow]);
  }
}

// ---------------------------------------------------------------------------
// Conv 3x3 SAME; 4 tokens per block. qh/kh: [B,H,N,96]; vtg: [B,H,96,N]
// transposed AND pre-scaled by G[n].
// ---------------------------------------------------------------------------
__global__ void conv_kernel(const float* __restrict__ q, const float* __restrict__ k,
                            const float* __restrict__ v,
                            const float* __restrict__ wq, const float* __restrict__ wk,
                            const float* __restrict__ wv,
                            const float* __restrict__ G,
                            unsigned short* __restrict__ qh, unsigned short* __restrict__ kh,
                            unsigned short* __restrict__ vtg)
{
  const int tb = blockIdx.x;         // 0..2047 (4 tokens each)
  const int which = blockIdx.y;      // 0=q 1=k 2=v
  const float* x = (which == 0) ? q : (which == 1) ? k : v;
  const float* w = (which == 0) ? wq : (which == 1) ? wk : wv;

  __shared__ float xs[4*768];
  __shared__ float wsm[81];
  const int tid = threadIdx.x;
  for (int i = tid; i < 4*768; i += 256) xs[i] = x[(size_t)tb*4*768 + i];
  if (tid < 81) wsm[tid] = w[tid];
  __syncthreads();

  for (int idx = tid; idx < 4*768; idx += 256){
    int tk = idx / 768, f = idx - tk*768;
    const float* xt = xs + tk*768;
    int co = f % 3;
    int pix = f / 3;
    int c = pix & 15, r = pix >> 4;
    float acc = 0.f;
#pragma unroll
    for (int dr = 0; dr < 3; ++dr){
      int rr = r + dr - 1;
      if (rr < 0 || rr > 15) continue;
#pragma unroll
      for (int dc = 0; dc < 3; ++dc){
        int cc = c + dc - 1;
        if (cc < 0 || cc > 15) continue;
#pragma unroll
        for (int ci = 0; ci < 3; ++ci)
          acc += xt[(rr*16 + cc)*3 + ci] * wsm[((dr*3 + dc)*3 + ci)*3 + co];
      }
    }
    int token = tb*4 + tk;
    int b = token >> 10, n = token & 1023;
    int h = f / 96, d = f - h*96;
    if (which == 2)
      vtg[((size_t)(b*8 + h)*96 + d)*1024 + n] = f2bf(acc * G[n]);
    else {
      unsigned short* dst = (which == 0) ? qh : kh;
      dst[((size_t)(b*8 + h)*1024 + n)*96 + d] = f2bf(acc);
    }
  }
}

// ---------------------------------------------------------------------------
// cv[bh][d] = sum_p CoverG[p] * vtg[bh][d][p]   (= sum_p Cc[p]*V[p][d])
// Grid 128: block = (bh, half); each wave handles d's strided by 4.
// ---------------------------------------------------------------------------
__global__ __launch_bounds__(256) void cv_kernel(const unsigned short* __restrict__ vtg,
                                                 const float* __restrict__ CoverG,
                                                 float* __restrict__ cv)
{
  const int id = blockIdx.x;
  const int bh = id >> 1;
  const int d0 = (id & 1) * 48;
  const int tid = threadIdx.x;
  const int w = tid >> 6, lane = tid & 63;
  const unsigned short* vb = vtg + (size_t)bh * 96 * 1024;

  for (int d = d0 + w; d < d0 + 48; d += 4){
    const unsigned short* row = vb + (size_t)d * 1024;
    float s = 0.f;
#pragma unroll
    for (int j = 0; j < 16; ++j){
      int p = j*64 + lane;
      s += CoverG[p] * bf2f(row[p]);
    }
#pragma unroll
    for (int off = 1; off < 64; off <<= 1) s += __shfl_xor(s, off);
    if (lane == 0) cv[(size_t)bh*96 + d] = s;
  }
}

// ---------------------------------------------------------------------------
// M2t[bh][d][m] = sum_p Wre_rm[m][p] * vtg[bh][d][p]   (K = 1024 over p)
// 512 blocks, XCD-swizzled so all 8 m-tiles of one bh share an XCD.
// ---------------------------------------------------------------------------
__global__ __launch_bounds__(256, 4) void m2_kernel(
    const unsigned short* __restrict__ Wre_rm, const unsigned short* __restrict__ vtg,
    unsigned short* __restrict__ M2t)
{
  const int id = blockIdx.x;             // 0..511
  const int xcd = id & 7, slot = id >> 3;
  const int mtile = slot & 7;            // 0..7
  const int bh = xcd + ((slot >> 3) << 3);
  const int tid = threadIdx.x;
  const int w = tid >> 6, lane = tid & 63, lh = lane >> 4, lm = lane & 15;
  const int m0 = mtile*128 + w*32;

  const unsigned short* vb = vtg + (size_t)bh * 96 * 1024;

  f32x4 acc[2][6];
#pragma unroll
  for (int rt = 0; rt < 2; ++rt)
#pragma unroll
    for (int dt = 0; dt < 6; ++dt)
      acc[rt][dt] = f32x4{0.f, 0.f, 0.f, 0.f};

  for (int ks = 0; ks < 32; ++ks){
    const int p0 = ks*32;
    bf16x8 aW[2];
#pragma unroll
    for (int rt = 0; rt < 2; ++rt)
      aW[rt] = ld8(Wre_rm + (size_t)(m0 + rt*16 + lm)*1024 + p0 + lh*8);
#pragma unroll
    for (int dt = 0; dt < 6; ++dt){
      bf16x8 bV = ld8(vb + (size_t)(dt*16 + lm)*1024 + p0 + lh*8);
#pragma unroll
      for (int rt = 0; rt < 2; ++rt)
        acc[rt][dt] = mfma16(aW[rt], bV, acc[rt][dt]);
    }
  }

#pragma unroll
  for (int rt = 0; rt < 2; ++rt)
#pragma unroll
    for (int dt = 0; dt < 6; ++dt)
#pragma unroll
      for (int rg = 0; rg < 4; ++rg){
        int m = m0 + rt*16 + lh*4 + rg;
        int d = dt*16 + lm;
        M2t[((size_t)bh*96 + d)*1024 + m] = f2bf(acc[rt][dt][rg]);
      }
}

// ---------------------------------------------------------------------------
// Fused attention: QK^T -> exp (unnormalized, deferred norm) -> P @ M2t.
// 32 rows/block, 512 threads = 8 waves; wave w owns 128-col slice in phase 1.
// Phase 3: 4-way K-split; 1/rowsum + cv folded into epilogue.
// XCD-swizzled: all 32 row-blocks of one bh on the same XCD (kh/M2t L2-hit).
// ---------------------------------------------------------------------------
__global__ __launch_bounds__(512, 4) void attn_kernel(
    const unsigned short* __restrict__ qh, const unsigned short* __restrict__ kh,
    const unsigned short* __restrict__ M2t, const float* __restrict__ cv,
    unsigned short* __restrict__ xh)
{
  constexpr int LDP = 1034;                        // padded P row (ushort): 2068 B
  __shared__ __align__(16) unsigned short p_lds[32 * LDP];   // 66176 B
  __shared__ float red[32][8];                                //  1024 B

  const int id = blockIdx.x;             // 0..2047
  const int xcd = id & 7, slot = id >> 3;
  const int rb = slot & 31;              // row block
  const int bh = xcd + ((slot >> 5) << 3);
  const int n0 = rb * 32;
  const int tid = threadIdx.x;
  const int w = tid >> 6;          // 0..7
  const int lane = tid & 63;
  const int lh = lane >> 4;        // 0..3
  const int lm = lane & 15;        // 0..15
  const int c0 = w * 128;

  const unsigned short* Qb = qh + (size_t)bh * 1024 * 96;
  const unsigned short* Kb = kh + (size_t)bh * 1024 * 96;
  const unsigned short* Mb = M2t + (size_t)bh * 96 * 1024;

  // ---- phase 1: S = Q K^T * scale, exp, row-sum -> red, raw P -> LDS ----
  // Max-subtraction dropped (|S*scale| <= ~8, exp safe in f32); normalization
  // deferred to the epilogue (P stored unnormalized).
  {
    bf16x8 aq[2][3];
#pragma unroll
    for (int rt = 0; rt < 2; ++rt)
#pragma unroll
      for (int kq = 0; kq < 3; ++kq)
        aq[rt][kq] = ld8(Qb + (size_t)(n0 + rt*16 + lm)*96 + kq*32 + lh*8);

    f32x4 acc[2][8];
#pragma unroll
    for (int rt = 0; rt < 2; ++rt)
#pragma unroll
      for (int nt = 0; nt < 8; ++nt)
        acc[rt][nt] = f32x4{0.f, 0.f, 0.f, 0.f};

#pragma unroll
    for (int nt = 0; nt < 8; ++nt){
#pragma unroll
      for (int kq = 0; kq < 3; ++kq){
        bf16x8 bk = ld8(Kb + (size_t)(c0 + nt*16 + lm)*96 + kq*32 + lh*8);
#pragma unroll
        for (int rt = 0; rt < 2; ++rt)
          acc[rt][nt] = mfma16(aq[rt][kq], bk, acc[rt][nt]);
      }
    }

    const float SCALE = 0.10206207261596577f;
#pragma unroll
    for (int rt = 0; rt < 2; ++rt)
#pragma unroll
      for (int rg = 0; rg < 4; ++rg){
        float s = 0.f;
#pragma unroll
        for (int nt = 0; nt < 8; ++nt){
          float e = __expf(acc[rt][nt][rg] * SCALE);
          acc[rt][nt][rg] = e;
          s += e;
        }
#pragma unroll
        for (int off = 1; off < 16; off <<= 1) s += __shfl_xor(s, off);
        if (lm == 0) red[rt*16 + lh*4 + rg][w] = s;
      }

#pragma unroll
    for (int rt = 0; rt < 2; ++rt)
#pragma unroll
      for (int nt = 0; nt < 8; ++nt)
#pragma unroll
        for (int rg = 0; rg < 4; ++rg)
          p_lds[(size_t)(rt*16 + lh*4 + rg)*LDP + c0 + nt*16 + lm] =
              f2bf(acc[rt][nt][rg]);
  }
  __syncthreads();   // P and red both visible

  // ---- phase 3: out = (P @ M2t^T)*rinv + cv ; 4-way K-split, 2 row-tiles ----
  {
    const int kw = w >> 1;       // 0..3 : k in [kw*256, kw*256+256)
    const int rt3 = w & 1;       // 16-row tile

    f32x4 acc3[6];
#pragma unroll
    for (int dt = 0; dt < 6; ++dt) acc3[dt] = f32x4{0.f, 0.f, 0.f, 0.f};

    for (int i = 0; i < 8; ++i){
      int kt = kw*8 + i;
      bf16x8 a = ld8(p_lds + (size_t)(rt3*16 + lm)*LDP + kt*32 + lh*8);
#pragma unroll
      for (int dt = 0; dt < 6; ++dt){
        bf16x8 bb = ld8(Mb + (size_t)(dt*16 + lm)*1024 + kt*32 + lh*8);
        acc3[dt] = mfma16(a, bb, acc3[dt]);
      }
    }
    __syncthreads();   // all P reads done; alias partial buffer onto p_lds

    float* part = reinterpret_cast<float*>(p_lds);   // 3 * 32 * 96 floats
    if (kw != 0){
#pragma unroll
      for (int dt = 0; dt < 6; ++dt)
#pragma unroll
        for (int rg = 0; rg < 4; ++rg)
          part[(size_t)(kw-1)*3072 + (rt3*16 + lh*4 + rg)*96 + dt*16 + lm] = acc3[dt][rg];
    }
    __syncthreads();
    if (kw == 0){
      float rinv[4];
#pragma unroll
      for (int rg = 0; rg < 4; ++rg){
        int row = rt3*16 + lh*4 + rg;
        float s = red[row][0];
#pragma unroll
        for (int j = 1; j < 8; ++j) s += red[row][j];
        rinv[rg] = 1.f / s;
      }
#pragma unroll
      for (int dt = 0; dt < 6; ++dt)
#pragma unroll
        for (int rg = 0; rg < 4; ++rg){
          int row = rt3*16 + lh*4 + rg;
          int col = dt*16 + lm;
          float s = (acc3[dt][rg] + part[row*96 + col]
                  + part[3072 + row*96 + col] + part[6144 + row*96 + col]) * rinv[rg]
                  + cv[(size_t)bh*96 + col];
          xh[((size_t)bh*1024 + n0 + row)*96 + col] = f2bf(s);
        }
    }
  }
}

// ---------------------------------------------------------------------------
// Projection: out[t][o] = sum_i xh[t][i] * w_proj[i][o] + b_proj[o]  (f32 out)
// ---------------------------------------------------------------------------
__global__ __launch_bounds__(256) void proj_kernel(
    const unsigned short* __restrict__ xh, const unsigned short* __restrict__ Wpt,
    const float* __restrict__ b_proj, float* __restrict__ out)
{
  const int mb = blockIdx.x;        // 0..127 -> 64 rows
  const int nb = blockIdx.y;        // 0..7   -> 96 cols
  const int tid = threadIdx.x;
  const int w = tid >> 6, lane = tid & 63, lh = lane >> 4, lm = lane & 15;
  const int t0 = mb*64 + w*16;
  const int o0 = nb*96;

  f32x4 acc[6];
#pragma unroll
  for (int nt = 0; nt < 6; ++nt) acc[nt] = f32x4{0.f, 0.f, 0.f, 0.f};

  const int t = t0 + lm;
  const int b = t >> 10, n = t & 1023;

  for (int kt = 0; kt < 24; ++kt){
    int i = kt*32 + lh*8;           // 32-chunks never cross a 96-head boundary
    int h = i / 96;
    int d = i - h*96;
    bf16x8 a = ld8(xh + ((size_t)(b*8 + h)*1024 + n)*96 + d);
#pragma unroll
    for (int nt = 0; nt < 6; ++nt){
      bf16x8 bv = ld8(Wpt + (size_t)(o0 + nt*16 + lm)*768 + kt*32 + lh*8);
      acc[nt] = mfma16(a, bv, acc[nt]);
    }
  }

#pragma unroll
  for (int nt = 0; nt < 6; ++nt){
    int o = o0 + nt*16 + lm;
    float bias = b_proj[o];
#pragma unroll
    for (int rg = 0; rg < 4; ++rg)
      out[(size_t)(t0 + lh*4 + rg)*768 + o] = acc[nt][rg] + bias;
  }
}

// ---------------------------------------------------------------------------
extern "C" void kernel_launch(void* const* d_in, const int* in_sizes, int n_in,
                              void* d_out, int out_size, void* d_ws, size_t ws_size,
                              hipStream_t stream)
{
  (void)in_sizes; (void)n_in; (void)out_size; (void)ws_size;
  const float* q      = (const float*)d_in[0];
  const float* k      = (const float*)d_in[1];
  const float* v      = (const float*)d_in[2];
  const float* wq     = (const float*)d_in[3];
  const float* wk     = (const float*)d_in[4];
  const float* wv     = (const float*)d_in[5];
  const float* w_re   = (const float*)d_in[6];
  const float* b_re   = (const float*)d_in[7];
  const float* gma    = (const float*)d_in[8];
  const float* beta   = (const float*)d_in[9];
  const float* mean   = (const float*)d_in[10];
  const float* var    = (const float*)d_in[11];
  const float* w_proj = (const float*)d_in[12];
  const float* b_proj = (const float*)d_in[13];
  float* out = (float*)d_out;

  // ws layout (bytes): total ~66.3 MB
  char* ws = (char*)d_ws;
  unsigned short* qh     = (unsigned short*)(ws + 0);          // 12,582,912
  unsigned short* kh     = (unsigned short*)(ws + 12582912);   // 12,582,912
  unsigned short* vtg    = (unsigned short*)(ws + 25165824);   // 12,582,912
  unsigned short* xh     = (unsigned short*)(ws + 37748736);   // 12,582,912
  unsigned short* Wre_rm = (unsigned short*)(ws + 50331648);   //  2,097,152
  unsigned short* Wpt    = (unsigned short*)(ws + 52428800);   //  1,179,648
  unsigned short* M2t    = (unsigned short*)(ws + 53608448);   // 12,582,912
  float*          G      = (float*)(ws + 66191360);            //      4,096
  float*          Cc     = (float*)(ws + 66195456);            //      4,096
  float*          CoverG = (float*)(ws + 66199552);            //      4,096
  float*          cv     = (float*)(ws + 66203648);            //     24,576

  prep_kernel<<<dim3(4100), dim3(256), 0, stream>>>(w_re, b_re, gma, beta, mean, var,
                                                    Wre_rm, G, Cc, CoverG);
  wpt_kernel<<<dim3(12, 12), dim3(256), 0, stream>>>(w_proj, Wpt);
  conv_kernel<<<dim3(2048, 3), dim3(256), 0, stream>>>(q, k, v, wq, wk, wv, G, qh, kh, vtg);
  cv_kernel<<<dim3(128), dim3(256), 0, stream>>>(vtg, CoverG, cv);
  m2_kernel<<<dim3(512), dim3(256), 0, stream>>>(Wre_rm, vtg, M2t);
  attn_kernel<<<dim3(2048), dim3(512), 0, stream>>>(qh, kh, M2t, cv, xh);
  proj_kernel<<<dim3(128, 8), dim3(256), 0, stream>>>(xh, Wpt, b_proj, out);
}

// Round 7
// 331.107 us; speedup vs baseline: 1.2388x; 1.2388x over previous
//
#include <hip/hip_runtime.h>
#include <hip/hip_bf16.h>

// Sizes
// B=8, N=1024, S=16, C=3, H=8, DIM=768, HD=96, SCALE=96^-0.5, BN_EPS=1e-3
//
// Algebraic restructuring (R5): out = BN(P@W_re)@V collapses to
//   out[n][d] = sum_m P[n][m] * M2[m][d] + cv[d]
//   M2[m][d]  = sum_p W_re[m][p] * G[p] * V[p][d]      (12.9 GF, batched bh)
//   cv[d]     = sum_p Cc[p] * V[p][d]
// R7: conv writes fully coalesced (V row-major, transposed to [d][n] by a
//     dedicated LDS-tile kernel); pixel-per-thread conv (3 outputs share the
//     27 LDS reads); cv at 512 blocks. attn/m2 swizzles kept from R6.

typedef __attribute__((ext_vector_type(4))) float f32x4;
typedef __bf16 __attribute__((ext_vector_type(8))) bf16x8;
typedef unsigned short u16x8 __attribute__((ext_vector_type(8)));

__device__ __forceinline__ unsigned short f2bf(float x){
  unsigned u = __builtin_bit_cast(unsigned, x);
  u += 0x7fffu + ((u >> 16) & 1u);          // round-to-nearest-even
  return (unsigned short)(u >> 16);
}

__device__ __forceinline__ float bf2f(unsigned short u){
  unsigned v = (unsigned)u << 16;
  return __builtin_bit_cast(float, v);
}

__device__ __forceinline__ f32x4 mfma16(bf16x8 a, bf16x8 b, f32x4 c){
  return __builtin_amdgcn_mfma_f32_16x16x32_bf16(a, b, c, 0, 0, 0);
}

__device__ __forceinline__ bf16x8 ld8(const unsigned short* p){
  return *reinterpret_cast<const bf16x8*>(p);
}

// ---------------------------------------------------------------------------
// Prep: Wre_rm[m][p] = bf16(w_re[m][p]) (coalesced cast);
//       G[p] = gamma*rsqrt(var+eps); Cc=(b_re-mean)*G+beta; CoverG=Cc/G
// ---------------------------------------------------------------------------
__global__ void prep_kernel(const float* __restrict__ w_re, const float* __restrict__ b_re,
                            const float* __restrict__ gma, const float* __restrict__ beta,
                            const float* __restrict__ mean, const float* __restrict__ var,
                            unsigned short* __restrict__ Wre_rm,
                            float* __restrict__ G, float* __restrict__ Cc,
                            float* __restrict__ CoverG)
{
  int idx = blockIdx.x * 256 + threadIdx.x;
  if (idx < 1024*1024){
    Wre_rm[idx] = f2bf(w_re[idx]);
  } else if (idx < 1024*1024 + 1024){
    int p = idx - 1024*1024;
    float g = gma[p] * rsqrtf(var[p] + 1e-3f);
    float cc = (b_re[p] - mean[p]) * g + beta[p];
    G[p] = g;
    Cc[p] = cc;
    CoverG[p] = cc / g;
  }
}

// ---------------------------------------------------------------------------
// Wpt[o][i] = bf16(w_proj[i][o]) via LDS 64x64 tiles (coalesced both sides)
// ---------------------------------------------------------------------------
__global__ __launch_bounds__(256) void wpt_kernel(const float* __restrict__ wp,
                                                  unsigned short* __restrict__ Wpt)
{
  __shared__ float t[64][65];
  const int i0 = blockIdx.x * 64, o0 = blockIdx.y * 64;
  const int r = threadIdx.x >> 6;        // 0..3
  const int c = threadIdx.x & 63;        // 0..63
#pragma unroll
  for (int rep = 0; rep < 16; ++rep){
    int row = rep*4 + r;
    t[row][c] = wp[(size_t)(i0 + row)*768 + o0 + c];
  }
  __syncthreads();
#pragma unroll
  for (int rep = 0; rep < 16; ++rep){
    int orow = rep*4 + r;
    Wpt[(size_t)(o0 + orow)*768 + i0 + c] = f2bf(t[c][orow]);
  }
}

// ---------------------------------------------------------------------------
// Conv 3x3 SAME; 4 tokens/block, pixel-per-thread (3 co outputs share reads).
// qh/kh/vh all [B,H,N,96] row-major (coalesced writes); vh pre-scaled by G[n].
// ---------------------------------------------------------------------------
__global__ __launch_bounds__(256) void conv_kernel(
    const float* __restrict__ q, const float* __restrict__ k,
    const float* __restrict__ v,
    const float* __restrict__ wq, const float* __restrict__ wk,
    const float* __restrict__ wv,
    const float* __restrict__ G,
    unsigned short* __restrict__ qh, unsigned short* __restrict__ kh,
    unsigned short* __restrict__ vh)
{
  const int tb = blockIdx.x;         // 0..2047 (4 tokens each)
  const int which = blockIdx.y;      // 0=q 1=k 2=v
  const float* x = (which == 0) ? q : (which == 1) ? k : v;
  const float* w = (which == 0) ? wq : (which == 1) ? wk : wv;
  unsigned short* dst = (which == 0) ? qh : (which == 1) ? kh : vh;

  __shared__ float xs[4*768];
  __shared__ float wsm[81];
  const int tid = threadIdx.x;
  for (int i = tid; i < 4*768; i += 256) xs[i] = x[(size_t)tb*4*768 + i];
  if (tid < 81) wsm[tid] = w[tid];
  __syncthreads();

  const int pix = tid;               // 0..255
  const int c = pix & 15, r = pix >> 4;

#pragma unroll
  for (int tk = 0; tk < 4; ++tk){
    const float* xt = xs + tk*768;
    float a0 = 0.f, a1 = 0.f, a2 = 0.f;
#pragma unroll
    for (int dr = 0; dr < 3; ++dr){
      int rr = r + dr - 1;
      if (rr < 0 || rr > 15) continue;
#pragma unroll
      for (int dc = 0; dc < 3; ++dc){
        int cc = c + dc - 1;
        if (cc < 0 || cc > 15) continue;
        const float* xp = xt + (rr*16 + cc)*3;
        const float* wp = wsm + (dr*3 + dc)*9;
#pragma unroll
        for (int ci = 0; ci < 3; ++ci){
          float xv = xp[ci];
          a0 += xv * wp[ci*3 + 0];
          a1 += xv * wp[ci*3 + 1];
          a2 += xv * wp[ci*3 + 2];
        }
      }
    }
    const int token = tb*4 + tk;
    const int b = token >> 10, n = token & 1023;
    const float gs = (which == 2) ? G[n] : 1.f;
    float av[3] = {a0*gs, a1*gs, a2*gs};
#pragma unroll
    for (int co = 0; co < 3; ++co){
      int f = pix*3 + co;                   // head boundary (96) never splits a thread
      int h = f / 96, d = f - h*96;
      dst[((size_t)(b*8 + h)*1024 + n)*96 + d] = f2bf(av[co]);
    }
  }
}

// ---------------------------------------------------------------------------
// Transpose vh[bh][n][96] -> vtg[bh][d][n] via LDS tile, coalesced both sides.
// Grid (8 n-chunks, 64 bh).
// ---------------------------------------------------------------------------
__global__ __launch_bounds__(256) void vt_kernel(const unsigned short* __restrict__ vh,
                                                 unsigned short* __restrict__ vtg)
{
  __shared__ unsigned short t[96*136];       // row d: stride 136 (272 B, 16B-aligned, odd*16B)
  const int chunk = blockIdx.x;              // 0..7
  const int bh = blockIdx.y;                 // 0..63
  const int n0 = chunk*128;
  const int tid = threadIdx.x;

  const unsigned short* src = vh + ((size_t)bh*1024 + n0)*96;
#pragma unroll
  for (int it = 0; it < 6; ++it){
    int idx = it*256 + tid;                  // 0..1535
    int row = idx / 12, v = idx - row*12;    // row 0..127, v 0..11
    u16x8 xv = *reinterpret_cast<const u16x8*>(src + row*96 + v*8);
#pragma unroll
    for (int j = 0; j < 8; ++j) t[(v*8 + j)*136 + row] = xv[j];
  }
  __syncthreads();

  unsigned short* dstp = vtg + (size_t)bh*96*1024 + n0;
#pragma unroll
  for (int it = 0; it < 6; ++it){
    int idx = it*256 + tid;                  // 0..1535
    int d = idx >> 4, ch = idx & 15;         // d 0..95, ch 0..15
    u16x8 xv = *reinterpret_cast<const u16x8*>(&t[d*136 + ch*8]);
    *reinterpret_cast<u16x8*>(dstp + (size_t)d*1024 + ch*8) = xv;
  }
}

// ---------------------------------------------------------------------------
// cv[bh][d] = sum_p CoverG[p] * vtg[bh][d][p]   (= sum_p Cc[p]*V[p][d])
// Grid 512: block = (bh, 12-d chunk); each wave handles 3 d's.
// ---------------------------------------------------------------------------
__global__ __launch_bounds__(256) void cv_kernel(const unsigned short* __restrict__ vtg,
                                                 const float* __restrict__ CoverG,
                                                 float* __restrict__ cv)
{
  const int id = blockIdx.x;
  const int bh = id >> 3;
  const int d0 = (id & 7) * 12;
  const int tid = threadIdx.x;
  const int w = tid >> 6, lane = tid & 63;
  const unsigned short* vb = vtg + (size_t)bh * 96 * 1024;

#pragma unroll
  for (int dd = 0; dd < 3; ++dd){
    int d = d0 + w*3 + dd;
    const unsigned short* row = vb + (size_t)d * 1024;
    float s = 0.f;
#pragma unroll
    for (int j = 0; j < 16; ++j){
      int p = j*64 + lane;
      s += CoverG[p] * bf2f(row[p]);
    }
#pragma unroll
    for (int off = 1; off < 64; off <<= 1) s += __shfl_xor(s, off);
    if (lane == 0) cv[(size_t)bh*96 + d] = s;
  }
}

// ---------------------------------------------------------------------------
// M2t[bh][d][m] = sum_p Wre_rm[m][p] * vtg[bh][d][p]   (K = 1024 over p)
// 512 blocks, XCD-swizzled so all 8 m-tiles of one bh share an XCD.
// ---------------------------------------------------------------------------
__global__ __launch_bounds__(256, 4) void m2_kernel(
    const unsigned short* __restrict__ Wre_rm, const unsigned short* __restrict__ vtg,
    unsigned short* __restrict__ M2t)
{
  const int id = blockIdx.x;             // 0..511
  const int xcd = id & 7, slot = id >> 3;
  const int mtile = slot & 7;            // 0..7
  const int bh = xcd + ((slot >> 3) << 3);
  const int tid = threadIdx.x;
  const int w = tid >> 6, lane = tid & 63, lh = lane >> 4, lm = lane & 15;
  const int m0 = mtile*128 + w*32;

  const unsigned short* vb = vtg + (size_t)bh * 96 * 1024;

  f32x4 acc[2][6];
#pragma unroll
  for (int rt = 0; rt < 2; ++rt)
#pragma unroll
    for (int dt = 0; dt < 6; ++dt)
      acc[rt][dt] = f32x4{0.f, 0.f, 0.f, 0.f};

  for (int ks = 0; ks < 32; ++ks){
    const int p0 = ks*32;
    bf16x8 aW[2];
#pragma unroll
    for (int rt = 0; rt < 2; ++rt)
      aW[rt] = ld8(Wre_rm + (size_t)(m0 + rt*16 + lm)*1024 + p0 + lh*8);
#pragma unroll
    for (int dt = 0; dt < 6; ++dt){
      bf16x8 bV = ld8(vb + (size_t)(dt*16 + lm)*1024 + p0 + lh*8);
#pragma unroll
      for (int rt = 0; rt < 2; ++rt)
        acc[rt][dt] = mfma16(aW[rt], bV, acc[rt][dt]);
    }
  }

#pragma unroll
  for (int rt = 0; rt < 2; ++rt)
#pragma unroll
    for (int dt = 0; dt < 6; ++dt)
#pragma unroll
      for (int rg = 0; rg < 4; ++rg){
        int m = m0 + rt*16 + lh*4 + rg;
        int d = dt*16 + lm;
        M2t[((size_t)bh*96 + d)*1024 + m] = f2bf(acc[rt][dt][rg]);
      }
}

// ---------------------------------------------------------------------------
// Fused attention: QK^T -> exp (unnormalized, deferred norm) -> P @ M2t.
// 32 rows/block, 512 threads = 8 waves; wave w owns 128-col slice in phase 1.
// Phase 3: 4-way K-split; 1/rowsum + cv folded into epilogue.
// XCD-swizzled: all 32 row-blocks of one bh on the same XCD (kh/M2t L2-hit).
// ---------------------------------------------------------------------------
__global__ __launch_bounds__(512, 4) void attn_kernel(
    const unsigned short* __restrict__ qh, const unsigned short* __restrict__ kh,
    const unsigned short* __restrict__ M2t, const float* __restrict__ cv,
    unsigned short* __restrict__ xh)
{
  constexpr int LDP = 1034;                        // padded P row (ushort): 2068 B
  __shared__ __align__(16) unsigned short p_lds[32 * LDP];   // 66176 B
  __shared__ float red[32][8];                                //  1024 B

  const int id = blockIdx.x;             // 0..2047
  const int xcd = id & 7, slot = id >> 3;
  const int rb = slot & 31;              // row block
  const int bh = xcd + ((slot >> 5) << 3);
  const int n0 = rb * 32;
  const int tid = threadIdx.x;
  const int w = tid >> 6;          // 0..7
  const int lane = tid & 63;
  const int lh = lane >> 4;        // 0..3
  const int lm = lane & 15;        // 0..15
  const int c0 = w * 128;

  const unsigned short* Qb = qh + (size_t)bh * 1024 * 96;
  const unsigned short* Kb = kh + (size_t)bh * 1024 * 96;
  const unsigned short* Mb = M2t + (size_t)bh * 96 * 1024;

  // ---- phase 1: S = Q K^T * scale, exp, row-sum -> red, raw P -> LDS ----
  {
    bf16x8 aq[2][3];
#pragma unroll
    for (int rt = 0; rt < 2; ++rt)
#pragma unroll
      for (int kq = 0; kq < 3; ++kq)
        aq[rt][kq] = ld8(Qb + (size_t)(n0 + rt*16 + lm)*96 + kq*32 + lh*8);

    f32x4 acc[2][8];
#pragma unroll
    for (int rt = 0; rt < 2; ++rt)
#pragma unroll
      for (int nt = 0; nt < 8; ++nt)
        acc[rt][nt] = f32x4{0.f, 0.f, 0.f, 0.f};

#pragma unroll
    for (int nt = 0; nt < 8; ++nt){
#pragma unroll
      for (int kq = 0; kq < 3; ++kq){
        bf16x8 bk = ld8(Kb + (size_t)(c0 + nt*16 + lm)*96 + kq*32 + lh*8);
#pragma unroll
        for (int rt = 0; rt < 2; ++rt)
          acc[rt][nt] = mfma16(aq[rt][kq], bk, acc[rt][nt]);
      }
    }

    const float SCALE = 0.10206207261596577f;
#pragma unroll
    for (int rt = 0; rt < 2; ++rt)
#pragma unroll
      for (int rg = 0; rg < 4; ++rg){
        float s = 0.f;
#pragma unroll
        for (int nt = 0; nt < 8; ++nt){
          float e = __expf(acc[rt][nt][rg] * SCALE);
          acc[rt][nt][rg] = e;
          s += e;
        }
#pragma unroll
        for (int off = 1; off < 16; off <<= 1) s += __shfl_xor(s, off);
        if (lm == 0) red[rt*16 + lh*4 + rg][w] = s;
      }

#pragma unroll
    for (int rt = 0; rt < 2; ++rt)
#pragma unroll
      for (int nt = 0; nt < 8; ++nt)
#pragma unroll
        for (int rg = 0; rg < 4; ++rg)
          p_lds[(size_t)(rt*16 + lh*4 + rg)*LDP + c0 + nt*16 + lm] =
              f2bf(acc[rt][nt][rg]);
  }
  __syncthreads();   // P and red both visible

  // ---- phase 3: out = (P @ M2t^T)*rinv + cv ; 4-way K-split, 2 row-tiles ----
  {
    const int kw = w >> 1;       // 0..3 : k in [kw*256, kw*256+256)
    const int rt3 = w & 1;       // 16-row tile

    f32x4 acc3[6];
#pragma unroll
    for (int dt = 0; dt < 6; ++dt) acc3[dt] = f32x4{0.f, 0.f, 0.f, 0.f};

    for (int i = 0; i < 8; ++i){
      int kt = kw*8 + i;
      bf16x8 a = ld8(p_lds + (size_t)(rt3*16 + lm)*LDP + kt*32 + lh*8);
#pragma unroll
      for (int dt = 0; dt < 6; ++dt){
        bf16x8 bb = ld8(Mb + (size_t)(dt*16 + lm)*1024 + kt*32 + lh*8);
        acc3[dt] = mfma16(a, bb, acc3[dt]);
      }
    }
    __syncthreads();   // all P reads done; alias partial buffer onto p_lds

    float* part = reinterpret_cast<float*>(p_lds);   // 3 * 32 * 96 floats
    if (kw != 0){
#pragma unroll
      for (int dt = 0; dt < 6; ++dt)
#pragma unroll
        for (int rg = 0; rg < 4; ++rg)
          part[(size_t)(kw-1)*3072 + (rt3*16 + lh*4 + rg)*96 + dt*16 + lm] = acc3[dt][rg];
    }
    __syncthreads();
    if (kw == 0){
      float rinv[4];
#pragma unroll
      for (int rg = 0; rg < 4; ++rg){
        int row = rt3*16 + lh*4 + rg;
        float s = red[row][0];
#pragma unroll
        for (int j = 1; j < 8; ++j) s += red[row][j];
        rinv[rg] = 1.f / s;
      }
#pragma unroll
      for (int dt = 0; dt < 6; ++dt)
#pragma unroll
        for (int rg = 0; rg < 4; ++rg){
          int row = rt3*16 + lh*4 + rg;
          int col = dt*16 + lm;
          float s = (acc3[dt][rg] + part[row*96 + col]
                  + part[3072 + row*96 + col] + part[6144 + row*96 + col]) * rinv[rg]
                  + cv[(size_t)bh*96 + col];
          xh[((size_t)bh*1024 + n0 + row)*96 + col] = f2bf(s);
        }
    }
  }
}

// ---------------------------------------------------------------------------
// Projection: out[t][o] = sum_i xh[t][i] * w_proj[i][o] + b_proj[o]  (f32 out)
// ---------------------------------------------------------------------------
__global__ __launch_bounds__(256) void proj_kernel(
    const unsigned short* __restrict__ xh, const unsigned short* __restrict__ Wpt,
    const float* __restrict__ b_proj, float* __restrict__ out)
{
  const int mb = blockIdx.x;        // 0..127 -> 64 rows
  const int nb = blockIdx.y;        // 0..7   -> 96 cols
  const int tid = threadIdx.x;
  const int w = tid >> 6, lane = tid & 63, lh = lane >> 4, lm = lane & 15;
  const int t0 = mb*64 + w*16;
  const int o0 = nb*96;

  f32x4 acc[6];
#pragma unroll
  for (int nt = 0; nt < 6; ++nt) acc[nt] = f32x4{0.f, 0.f, 0.f, 0.f};

  const int t = t0 + lm;
  const int b = t >> 10, n = t & 1023;

  for (int kt = 0; kt < 24; ++kt){
    int i = kt*32 + lh*8;           // 32-chunks never cross a 96-head boundary
    int h = i / 96;
    int d = i - h*96;
    bf16x8 a = ld8(xh + ((size_t)(b*8 + h)*1024 + n)*96 + d);
#pragma unroll
    for (int nt = 0; nt < 6; ++nt){
      bf16x8 bv = ld8(Wpt + (size_t)(o0 + nt*16 + lm)*768 + kt*32 + lh*8);
      acc[nt] = mfma16(a, bv, acc[nt]);
    }
  }

#pragma unroll
  for (int nt = 0; nt < 6; ++nt){
    int o = o0 + nt*16 + lm;
    float bias = b_proj[o];
#pragma unroll
    for (int rg = 0; rg < 4; ++rg)
      out[(size_t)(t0 + lh*4 + rg)*768 + o] = acc[nt][rg] + bias;
  }
}

// ---------------------------------------------------------------------------
extern "C" void kernel_launch(void* const* d_in, const int* in_sizes, int n_in,
                              void* d_out, int out_size, void* d_ws, size_t ws_size,
                              hipStream_t stream)
{
  (void)in_sizes; (void)n_in; (void)out_size; (void)ws_size;
  const float* q      = (const float*)d_in[0];
  const float* k      = (const float*)d_in[1];
  const float* v      = (const float*)d_in[2];
  const float* wq     = (const float*)d_in[3];
  const float* wk     = (const float*)d_in[4];
  const float* wv     = (const float*)d_in[5];
  const float* w_re   = (const float*)d_in[6];
  const float* b_re   = (const float*)d_in[7];
  const float* gma    = (const float*)d_in[8];
  const float* beta   = (const float*)d_in[9];
  const float* mean   = (const float*)d_in[10];
  const float* var    = (const float*)d_in[11];
  const float* w_proj = (const float*)d_in[12];
  const float* b_proj = (const float*)d_in[13];
  float* out = (float*)d_out;

  // ws layout (bytes): total ~66.3 MB. vh aliases the xh slot (vh is dead
  // before attn writes xh).
  char* ws = (char*)d_ws;
  unsigned short* qh     = (unsigned short*)(ws + 0);          // 12,582,912
  unsigned short* kh     = (unsigned short*)(ws + 12582912);   // 12,582,912
  unsigned short* vtg    = (unsigned short*)(ws + 25165824);   // 12,582,912
  unsigned short* xh     = (unsigned short*)(ws + 37748736);   // 12,582,912
  unsigned short* vh     = xh;                                 // alias (dead before attn)
  unsigned short* Wre_rm = (unsigned short*)(ws + 50331648);   //  2,097,152
  unsigned short* Wpt    = (unsigned short*)(ws + 52428800);   //  1,179,648
  unsigned short* M2t    = (unsigned short*)(ws + 53608448);   // 12,582,912
  float*          G      = (float*)(ws + 66191360);            //      4,096
  float*          Cc     = (float*)(ws + 66195456);            //      4,096
  float*          CoverG = (float*)(ws + 66199552);            //      4,096
  float*          cv     = (float*)(ws + 66203648);            //     24,576

  prep_kernel<<<dim3(4100), dim3(256), 0, stream>>>(w_re, b_re, gma, beta, mean, var,
                                                    Wre_rm, G, Cc, CoverG);
  wpt_kernel<<<dim3(12, 12), dim3(256), 0, stream>>>(w_proj, Wpt);
  conv_kernel<<<dim3(2048, 3), dim3(256), 0, stream>>>(q, k, v, wq, wk, wv, G, qh, kh, vh);
  vt_kernel<<<dim3(8, 64), dim3(256), 0, stream>>>(vh, vtg);
  cv_kernel<<<dim3(512), dim3(256), 0, stream>>>(vtg, CoverG, cv);
  m2_kernel<<<dim3(512), dim3(256), 0, stream>>>(Wre_rm, vtg, M2t);
  attn_kernel<<<dim3(2048), dim3(512), 0, stream>>>(qh, kh, M2t, cv, xh);
  proj_kernel<<<dim3(128, 8), dim3(256), 0, stream>>>(xh, Wpt, b_proj, out);
}